// Round 7
// baseline (1242.105 us; speedup 1.0000x reference)
//
#include <hip/hip_runtime.h>
#include <hip/hip_fp16.h>
#include <hip/hip_cooperative_groups.h>
#include <math.h>

namespace cg = cooperative_groups;

#define N_NODES 50000
#define N_EDGES 800000
#define IN_FEATS 128
#define N_HIDDEN 64
#define OUT_FEATS 40
#define DIM 8
#define SCAN_NB ((N_NODES + 255) / 256)   // 196
#define GRID_BLOCKS 1024
#define BLOCK 256

// ---------------- wave-wide inclusive scan (64 lanes) ----------------
__device__ __forceinline__ int wave_incl_scan(int x, int lane) {
#pragma unroll
    for (int off = 1; off < 64; off <<= 1) {
        int v = __shfl_up(x, off, 64);
        if (lane >= off) x += v;
    }
    return x;
}

// ============================================================================
// Fused cooperative kernel: all phases, grid.sync() between them.
// 1024 blocks x 256 thr, launch_bounds(256,4) -> 4 blocks/CU guaranteed.
// ============================================================================
__global__ __launch_bounds__(256, 4) void fused_kernel(
    const float* __restrict__ features, const float* __restrict__ ew,
    const int* __restrict__ src, const int* __restrict__ dst,
    const float* __restrict__ W1, const float* __restrict__ b1,
    const float* __restrict__ mu1, const float* __restrict__ is1,
    const float* __restrict__ W2, const float* __restrict__ b2,
    const float* __restrict__ mu2, const float* __restrict__ is2,
    int2* __restrict__ csr, __half* __restrict__ h1, __half* __restrict__ h2,
    int* __restrict__ counts, int* __restrict__ cursor,
    int* __restrict__ offsets, int* __restrict__ blkSums,
    float* __restrict__ out)
{
    cg::grid_group grid = cg::this_grid();
    const int tid  = threadIdx.x;
    const int bid  = blockIdx.x;
    const int gtid = bid * BLOCK + tid;
    const int GSZ  = GRID_BLOCKS * BLOCK;
    const int lane = tid & 63, wid = tid >> 6;

    __shared__ float ldsf[4 * 4 * 132];   // 8448 B, aliased per phase

    // ---- P0: zero counts ----
    for (int i = gtid; i < N_NODES; i += GSZ) counts[i] = 0;
    grid.sync();

    // ---- P1: in-degree histogram ----
    for (int e = gtid; e < N_EDGES; e += GSZ) atomicAdd(&counts[dst[e]], 1);
    grid.sync();

    // ---- P2a: block-local exclusive scan + block totals (blocks 0..195) ----
    {
        int* wsum = (int*)ldsf;
        if (bid < SCAN_NB) {
            int i = gtid;
            int x = (i < N_NODES) ? counts[i] : 0;
            int incl = wave_incl_scan(x, lane);
            if (lane == 63) wsum[wid] = incl;
            __syncthreads();
            int base = 0;
#pragma unroll
            for (int w = 0; w < 4; ++w)
                if (w < wid) base += wsum[w];
            if (i < N_NODES) offsets[i] = base + incl - x;   // block-local exclusive
            if (tid == 255) blkSums[bid] = base + incl;      // block total
        }
    }
    grid.sync();

    // ---- P2b: block 0 scans the 196 block totals (exclusive) ----
    {
        int* wsum = (int*)ldsf;
        if (bid == 0) {
            int i = tid;
            int x = (i < SCAN_NB) ? blkSums[i] : 0;
            int incl = wave_incl_scan(x, lane);
            if (lane == 63) wsum[wid] = incl;
            __syncthreads();
            int base = 0;
#pragma unroll
            for (int w = 0; w < 4; ++w)
                if (w < wid) base += wsum[w];
            if (i < SCAN_NB) blkSums[i] = base + incl - x;
        }
    }
    grid.sync();

    // ---- P2c: add block bases, emit offsets + cursor ----
    for (int i = gtid; i < N_NODES; i += GSZ) {
        int v = offsets[i] + blkSums[i >> 8];
        offsets[i] = v;
        cursor[i]  = v;
    }
    if (gtid == 0) offsets[N_NODES] = N_EDGES;
    grid.sync();

    // ---- P3: CSR fill, one 8B store per edge {src, (g1,g2):half2} ----
    for (int e = gtid; e < N_EDGES; e += GSZ) {
        float s1 = 0.f, s2 = 0.f;
#pragma unroll
        for (int d = 0; d < DIM; ++d) {
            float v = ew[e * DIM + d];
            float d1 = v - mu1[d]; float a1 = is1[d];
            float d2 = v - mu2[d]; float a2 = is2[d];
            s1 += d1 * d1 * a1 * a1;
            s2 += d2 * d2 * a2 * a2;
        }
        int pos = atomicAdd(&cursor[dst[e]], 1);
        __half2 g = __floats2half2_rn(expf(-0.5f * s1), expf(-0.5f * s2));
        int2 rec;
        rec.x = src[e];
        rec.y = *reinterpret_cast<int*>(&g);
        csr[pos] = rec;
    }
    grid.sync();

    // ---- P4: h1 = features @ W1 -> fp16 (wave = 4 nodes, wave-private LDS) ----
    {
        float (*xs)[4][132] = (float(*)[4][132])ldsf;
        const float4* W4 = (const float4*)W1;
        for (int tile = bid; tile < N_NODES / 16; tile += GRID_BLOCKS) {
            int ns = lane >> 4, f4 = lane & 15;
            int nodeBase = tile * 16 + wid * 4;
#pragma unroll
            for (int i = 0; i < 8; ++i) {
                int idx = lane + i * 64;
                int nn = idx >> 7, k = idx & 127;
                xs[wid][nn][k] = features[(size_t)(nodeBase + nn) * IN_FEATS + k];
            }
            float4 acc = make_float4(0.f, 0.f, 0.f, 0.f);
#pragma unroll 4
            for (int k = 0; k < IN_FEATS; ++k) {
                float xv = xs[wid][ns][k];
                float4 w = W4[k * 16 + f4];
                acc.x += xv * w.x; acc.y += xv * w.y;
                acc.z += xv * w.z; acc.w += xv * w.w;
            }
            int n = nodeBase + ns;
            __half2 lo = __floats2half2_rn(acc.x, acc.y);
            __half2 hi = __floats2half2_rn(acc.z, acc.w);
            uint2 pk;
            pk.x = *reinterpret_cast<unsigned*>(&lo);
            pk.y = *reinterpret_cast<unsigned*>(&hi);
            *reinterpret_cast<uint2*>(&h1[(size_t)n * N_HIDDEN + 4 * f4]) = pk;
        }
    }
    grid.sync();

    // ---- P5: agg1 + gemm2 fused (wave = 1 node) ----
    {
        float* axs = ldsf;
        for (int grp = bid; grp < N_NODES / 4; grp += GRID_BLOCKS) {
            int n = grp * 4 + wid;
            int beg = offsets[n], end = offsets[n + 1];
            float a0 = 0.f, a1 = 0.f, a2 = 0.f, a3 = 0.f;
            int j = beg;
            for (; j + 8 <= end; j += 8) {
                int2 c0 = csr[j + 0], c1 = csr[j + 1], c2 = csr[j + 2], c3 = csr[j + 3];
                int2 c4 = csr[j + 4], c5 = csr[j + 5], c6 = csr[j + 6], c7 = csr[j + 7];
                float v0 = __half2float(h1[(size_t)c0.x * N_HIDDEN + lane]);
                float v1 = __half2float(h1[(size_t)c1.x * N_HIDDEN + lane]);
                float v2 = __half2float(h1[(size_t)c2.x * N_HIDDEN + lane]);
                float v3 = __half2float(h1[(size_t)c3.x * N_HIDDEN + lane]);
                float v4 = __half2float(h1[(size_t)c4.x * N_HIDDEN + lane]);
                float v5 = __half2float(h1[(size_t)c5.x * N_HIDDEN + lane]);
                float v6 = __half2float(h1[(size_t)c6.x * N_HIDDEN + lane]);
                float v7 = __half2float(h1[(size_t)c7.x * N_HIDDEN + lane]);
                a0 += v0 * __low2float(*reinterpret_cast<__half2*>(&c0.y));
                a1 += v1 * __low2float(*reinterpret_cast<__half2*>(&c1.y));
                a2 += v2 * __low2float(*reinterpret_cast<__half2*>(&c2.y));
                a3 += v3 * __low2float(*reinterpret_cast<__half2*>(&c3.y));
                a0 += v4 * __low2float(*reinterpret_cast<__half2*>(&c4.y));
                a1 += v5 * __low2float(*reinterpret_cast<__half2*>(&c5.y));
                a2 += v6 * __low2float(*reinterpret_cast<__half2*>(&c6.y));
                a3 += v7 * __low2float(*reinterpret_cast<__half2*>(&c7.y));
            }
            for (; j < end; ++j) {
                int2 c = csr[j];
                a0 += __half2float(h1[(size_t)c.x * N_HIDDEN + lane]) *
                      __low2float(*reinterpret_cast<__half2*>(&c.y));
            }
            float x = (a0 + a1) + (a2 + a3) + b1[lane];

            axs[wid * N_HIDDEN + lane] = x;   // wave-private: no barrier
            if (lane < OUT_FEATS) {
                const float* xr = &axs[wid * N_HIDDEN];
                float acc = 0.f;
#pragma unroll
                for (int k = 0; k < N_HIDDEN; ++k)
                    acc += xr[k] * W2[k * OUT_FEATS + lane];
                h2[(size_t)n * OUT_FEATS + lane] = __float2half(acc);
            }
        }
    }
    grid.sync();

    // ---- P6: agg2 + b2 + log_softmax ----
    {
        for (int grp = bid; grp < N_NODES / 4; grp += GRID_BLOCKS) {
            int n = grp * 4 + wid;
            int tc = (lane < OUT_FEATS) ? lane : (OUT_FEATS - 1);
            int beg = offsets[n], end = offsets[n + 1];
            float a0 = 0.f, a1 = 0.f, a2 = 0.f, a3 = 0.f;
            int j = beg;
            for (; j + 8 <= end; j += 8) {
                int2 c0 = csr[j + 0], c1 = csr[j + 1], c2 = csr[j + 2], c3 = csr[j + 3];
                int2 c4 = csr[j + 4], c5 = csr[j + 5], c6 = csr[j + 6], c7 = csr[j + 7];
                float v0 = __half2float(h2[(size_t)c0.x * OUT_FEATS + tc]);
                float v1 = __half2float(h2[(size_t)c1.x * OUT_FEATS + tc]);
                float v2 = __half2float(h2[(size_t)c2.x * OUT_FEATS + tc]);
                float v3 = __half2float(h2[(size_t)c3.x * OUT_FEATS + tc]);
                float v4 = __half2float(h2[(size_t)c4.x * OUT_FEATS + tc]);
                float v5 = __half2float(h2[(size_t)c5.x * OUT_FEATS + tc]);
                float v6 = __half2float(h2[(size_t)c6.x * OUT_FEATS + tc]);
                float v7 = __half2float(h2[(size_t)c7.x * OUT_FEATS + tc]);
                a0 += v0 * __high2float(*reinterpret_cast<__half2*>(&c0.y));
                a1 += v1 * __high2float(*reinterpret_cast<__half2*>(&c1.y));
                a2 += v2 * __high2float(*reinterpret_cast<__half2*>(&c2.y));
                a3 += v3 * __high2float(*reinterpret_cast<__half2*>(&c3.y));
                a0 += v4 * __high2float(*reinterpret_cast<__half2*>(&c4.y));
                a1 += v5 * __high2float(*reinterpret_cast<__half2*>(&c5.y));
                a2 += v6 * __high2float(*reinterpret_cast<__half2*>(&c6.y));
                a3 += v7 * __high2float(*reinterpret_cast<__half2*>(&c7.y));
            }
            for (; j < end; ++j) {
                int2 c = csr[j];
                a0 += __half2float(h2[(size_t)c.x * OUT_FEATS + tc]) *
                      __high2float(*reinterpret_cast<__half2*>(&c.y));
            }
            float acc = (a0 + a1) + (a2 + a3);

            float v = (lane < OUT_FEATS) ? acc + b2[lane] : -INFINITY;
            float m = v;
#pragma unroll
            for (int off = 32; off; off >>= 1)
                m = fmaxf(m, __shfl_xor(m, off, 64));
            float ex = (lane < OUT_FEATS) ? expf(v - m) : 0.f;
            float s = ex;
#pragma unroll
            for (int off = 32; off; off >>= 1)
                s += __shfl_xor(s, off, 64);
            if (lane < OUT_FEATS)
                out[n * OUT_FEATS + lane] = v - m - logf(s);
        }
    }
}

// ============================================================================
// Fallback multi-kernel path (identical to R6) — used if cooperative launch
// is rejected under graph capture.
// ============================================================================
__global__ void hist_kernel(const int* __restrict__ dst, int* __restrict__ counts) {
    int e = blockIdx.x * blockDim.x + threadIdx.x;
    if (e < N_EDGES) atomicAdd(&counts[dst[e]], 1);
}

__global__ __launch_bounds__(256) void scan_blk_kernel(const int* __restrict__ counts,
                                                       int* __restrict__ offsets,
                                                       int* __restrict__ blkSums) {
    int i = blockIdx.x * 256 + threadIdx.x;
    int lane = threadIdx.x & 63, wid = threadIdx.x >> 6;
    int x = (i < N_NODES) ? counts[i] : 0;
    int incl = wave_incl_scan(x, lane);
    __shared__ int wsum[4];
    if (lane == 63) wsum[wid] = incl;
    __syncthreads();
    int base = 0;
#pragma unroll
    for (int w = 0; w < 4; ++w)
        if (w < wid) base += wsum[w];
    if (i < N_NODES) offsets[i] = base + incl - x;
    if (threadIdx.x == 255) blkSums[blockIdx.x] = base + incl;
}

__global__ __launch_bounds__(256) void scan_top_kernel(int* __restrict__ blkSums) {
    int i = threadIdx.x;
    int lane = i & 63, wid = i >> 6;
    int x = (i < SCAN_NB) ? blkSums[i] : 0;
    int incl = wave_incl_scan(x, lane);
    __shared__ int wsum[4];
    if (lane == 63) wsum[wid] = incl;
    __syncthreads();
    int base = 0;
#pragma unroll
    for (int w = 0; w < 4; ++w)
        if (w < wid) base += wsum[w];
    if (i < SCAN_NB) blkSums[i] = base + incl - x;
}

__global__ __launch_bounds__(256) void scan_add_kernel(int* __restrict__ offsets,
                                                       const int* __restrict__ blkSums,
                                                       int* __restrict__ cursor) {
    int i = blockIdx.x * 256 + threadIdx.x;
    if (i < N_NODES) {
        int v = offsets[i] + blkSums[blockIdx.x];
        offsets[i] = v;
        cursor[i]  = v;
    }
    if (blockIdx.x == 0 && threadIdx.x == 0)
        offsets[N_NODES] = N_EDGES;
}

__global__ void fill_kernel(const int* __restrict__ src, const int* __restrict__ dst,
                            const float* __restrict__ ew,
                            const float* __restrict__ mu1, const float* __restrict__ is1,
                            const float* __restrict__ mu2, const float* __restrict__ is2,
                            int* __restrict__ cursor,
                            int2* __restrict__ csr) {
    int e = blockIdx.x * blockDim.x + threadIdx.x;
    if (e >= N_EDGES) return;
    float s1 = 0.f, s2 = 0.f;
#pragma unroll
    for (int d = 0; d < DIM; ++d) {
        float v = ew[e * DIM + d];
        float d1 = v - mu1[d]; float a1 = is1[d];
        float d2 = v - mu2[d]; float a2 = is2[d];
        s1 += d1 * d1 * a1 * a1;
        s2 += d2 * d2 * a2 * a2;
    }
    int pos = atomicAdd(&cursor[dst[e]], 1);
    __half2 g = __floats2half2_rn(expf(-0.5f * s1), expf(-0.5f * s2));
    int2 rec;
    rec.x = src[e];
    rec.y = *reinterpret_cast<int*>(&g);
    csr[pos] = rec;
}

__global__ __launch_bounds__(256) void gemm1_kernel(const float* __restrict__ x,
                                                    const float* __restrict__ W,
                                                    __half* __restrict__ h) {
    __shared__ float xs[4][4][132];
    int wid = threadIdx.x >> 6, lane = threadIdx.x & 63;
    int ns = lane >> 4, f4 = lane & 15;
    int nodeBase = blockIdx.x * 16 + wid * 4;
#pragma unroll
    for (int i = 0; i < 8; ++i) {
        int idx = lane + i * 64;
        int nn = idx >> 7, k = idx & 127;
        xs[wid][nn][k] = x[(size_t)(nodeBase + nn) * IN_FEATS + k];
    }
    const float4* W4 = (const float4*)W;
    float4 acc = make_float4(0.f, 0.f, 0.f, 0.f);
#pragma unroll 4
    for (int k = 0; k < IN_FEATS; ++k) {
        float xv = xs[wid][ns][k];
        float4 w = W4[k * 16 + f4];
        acc.x += xv * w.x; acc.y += xv * w.y;
        acc.z += xv * w.z; acc.w += xv * w.w;
    }
    int n = nodeBase + ns;
    __half2 lo = __floats2half2_rn(acc.x, acc.y);
    __half2 hi = __floats2half2_rn(acc.z, acc.w);
    uint2 pk;
    pk.x = *reinterpret_cast<unsigned*>(&lo);
    pk.y = *reinterpret_cast<unsigned*>(&hi);
    *reinterpret_cast<uint2*>(&h[(size_t)n * N_HIDDEN + 4 * f4]) = pk;
}

__global__ __launch_bounds__(256) void agg1_gemm2_kernel(const __half* __restrict__ h,
                                                         const int* __restrict__ offsets,
                                                         const int2* __restrict__ csr,
                                                         const float* __restrict__ b,
                                                         const float* __restrict__ W2,
                                                         __half* __restrict__ h2) {
    __shared__ float xs[4 * N_HIDDEN];
    int wid = threadIdx.x >> 6;
    int t   = threadIdx.x & 63;
    int n   = blockIdx.x * 4 + wid;
    int beg = offsets[n], end = offsets[n + 1];
    float a0 = 0.f, a1 = 0.f, a2 = 0.f, a3 = 0.f;
    int j = beg;
    for (; j + 8 <= end; j += 8) {
        int2 c0 = csr[j + 0], c1 = csr[j + 1], c2 = csr[j + 2], c3 = csr[j + 3];
        int2 c4 = csr[j + 4], c5 = csr[j + 5], c6 = csr[j + 6], c7 = csr[j + 7];
        float v0 = __half2float(h[(size_t)c0.x * N_HIDDEN + t]);
        float v1 = __half2float(h[(size_t)c1.x * N_HIDDEN + t]);
        float v2 = __half2float(h[(size_t)c2.x * N_HIDDEN + t]);
        float v3 = __half2float(h[(size_t)c3.x * N_HIDDEN + t]);
        float v4 = __half2float(h[(size_t)c4.x * N_HIDDEN + t]);
        float v5 = __half2float(h[(size_t)c5.x * N_HIDDEN + t]);
        float v6 = __half2float(h[(size_t)c6.x * N_HIDDEN + t]);
        float v7 = __half2float(h[(size_t)c7.x * N_HIDDEN + t]);
        a0 += v0 * __low2float(*reinterpret_cast<__half2*>(&c0.y));
        a1 += v1 * __low2float(*reinterpret_cast<__half2*>(&c1.y));
        a2 += v2 * __low2float(*reinterpret_cast<__half2*>(&c2.y));
        a3 += v3 * __low2float(*reinterpret_cast<__half2*>(&c3.y));
        a0 += v4 * __low2float(*reinterpret_cast<__half2*>(&c4.y));
        a1 += v5 * __low2float(*reinterpret_cast<__half2*>(&c5.y));
        a2 += v6 * __low2float(*reinterpret_cast<__half2*>(&c6.y));
        a3 += v7 * __low2float(*reinterpret_cast<__half2*>(&c7.y));
    }
    for (; j < end; ++j) {
        int2 c = csr[j];
        a0 += __half2float(h[(size_t)c.x * N_HIDDEN + t]) *
              __low2float(*reinterpret_cast<__half2*>(&c.y));
    }
    float x = (a0 + a1) + (a2 + a3) + b[t];
    xs[wid * N_HIDDEN + t] = x;
    if (t < OUT_FEATS) {
        const float* xr = &xs[wid * N_HIDDEN];
        float acc = 0.f;
#pragma unroll
        for (int k = 0; k < N_HIDDEN; ++k)
            acc += xr[k] * W2[k * OUT_FEATS + t];
        h2[(size_t)n * OUT_FEATS + t] = __float2half(acc);
    }
}

__global__ __launch_bounds__(256) void agg2_kernel(const __half* __restrict__ h,
                                                   const int* __restrict__ offsets,
                                                   const int2* __restrict__ csr,
                                                   const float* __restrict__ b,
                                                   float* __restrict__ out) {
    int n = blockIdx.x * 4 + (threadIdx.x >> 6);
    int t = threadIdx.x & 63;
    if (n >= N_NODES) return;
    int tc = (t < OUT_FEATS) ? t : (OUT_FEATS - 1);
    int beg = offsets[n], end = offsets[n + 1];
    float a0 = 0.f, a1 = 0.f, a2 = 0.f, a3 = 0.f;
    int j = beg;
    for (; j + 8 <= end; j += 8) {
        int2 c0 = csr[j + 0], c1 = csr[j + 1], c2 = csr[j + 2], c3 = csr[j + 3];
        int2 c4 = csr[j + 4], c5 = csr[j + 5], c6 = csr[j + 6], c7 = csr[j + 7];
        float v0 = __half2float(h[(size_t)c0.x * OUT_FEATS + tc]);
        float v1 = __half2float(h[(size_t)c1.x * OUT_FEATS + tc]);
        float v2 = __half2float(h[(size_t)c2.x * OUT_FEATS + tc]);
        float v3 = __half2float(h[(size_t)c3.x * OUT_FEATS + tc]);
        float v4 = __half2float(h[(size_t)c4.x * OUT_FEATS + tc]);
        float v5 = __half2float(h[(size_t)c5.x * OUT_FEATS + tc]);
        float v6 = __half2float(h[(size_t)c6.x * OUT_FEATS + tc]);
        float v7 = __half2float(h[(size_t)c7.x * OUT_FEATS + tc]);
        a0 += v0 * __high2float(*reinterpret_cast<__half2*>(&c0.y));
        a1 += v1 * __high2float(*reinterpret_cast<__half2*>(&c1.y));
        a2 += v2 * __high2float(*reinterpret_cast<__half2*>(&c2.y));
        a3 += v3 * __high2float(*reinterpret_cast<__half2*>(&c3.y));
        a0 += v4 * __high2float(*reinterpret_cast<__half2*>(&c4.y));
        a1 += v5 * __high2float(*reinterpret_cast<__half2*>(&c5.y));
        a2 += v6 * __high2float(*reinterpret_cast<__half2*>(&c6.y));
        a3 += v7 * __high2float(*reinterpret_cast<__half2*>(&c7.y));
    }
    for (; j < end; ++j) {
        int2 c = csr[j];
        a0 += __half2float(h[(size_t)c.x * OUT_FEATS + tc]) *
              __high2float(*reinterpret_cast<__half2*>(&c.y));
    }
    float acc = (a0 + a1) + (a2 + a3);
    float v = (t < OUT_FEATS) ? acc + b[t] : -INFINITY;
    float m = v;
#pragma unroll
    for (int off = 32; off; off >>= 1)
        m = fmaxf(m, __shfl_xor(m, off, 64));
    float ex = (t < OUT_FEATS) ? expf(v - m) : 0.f;
    float s = ex;
#pragma unroll
    for (int off = 32; off; off >>= 1)
        s += __shfl_xor(s, off, 64);
    if (t < OUT_FEATS)
        out[n * OUT_FEATS + t] = v - m - logf(s);
}

extern "C" void kernel_launch(void* const* d_in, const int* in_sizes, int n_in,
                              void* d_out, int out_size, void* d_ws, size_t ws_size,
                              hipStream_t stream) {
    const float* features    = (const float*)d_in[0];
    const float* edge_weight = (const float*)d_in[1];
    const int*   src         = (const int*)d_in[2];
    const int*   dst         = (const int*)d_in[3];
    const float* W1          = (const float*)d_in[4];
    const float* b1          = (const float*)d_in[5];
    const float* mu1         = (const float*)d_in[6];
    const float* is1         = (const float*)d_in[7];
    const float* W2          = (const float*)d_in[8];
    const float* b2          = (const float*)d_in[9];
    const float* mu2         = (const float*)d_in[10];
    const float* is2         = (const float*)d_in[11];
    float* out = (float*)d_out;

    // Workspace: csr int2[800k] | h1 half[3.2M] | h2 half[2M] | counts | cursor | offsets | blkSums
    int2*   csr    = (int2*)d_ws;
    __half* h1     = (__half*)(csr + N_EDGES);
    __half* h2     = h1 + (size_t)N_NODES * N_HIDDEN;
    int*    counts = (int*)(h2 + (size_t)N_NODES * OUT_FEATS);
    int*    cursor = counts + N_NODES;
    int*    offsets= cursor + N_NODES;
    int*    blkSums= offsets + N_NODES + 1;

    void* args[] = {
        (void*)&features, (void*)&edge_weight, (void*)&src, (void*)&dst,
        (void*)&W1, (void*)&b1, (void*)&mu1, (void*)&is1,
        (void*)&W2, (void*)&b2, (void*)&mu2, (void*)&is2,
        (void*)&csr, (void*)&h1, (void*)&h2,
        (void*)&counts, (void*)&cursor, (void*)&offsets, (void*)&blkSums,
        (void*)&out
    };
    hipError_t err = hipLaunchCooperativeKernel((const void*)fused_kernel,
                                                dim3(GRID_BLOCKS), dim3(BLOCK),
                                                (void**)args, 0, stream);
    if (err != hipSuccess) {
        // Fallback: R6 multi-kernel path
        hipMemsetAsync(counts, 0, N_NODES * sizeof(int), stream);
        hist_kernel<<<(N_EDGES + 255) / 256, 256, 0, stream>>>(dst, counts);
        scan_blk_kernel<<<SCAN_NB, 256, 0, stream>>>(counts, offsets, blkSums);
        scan_top_kernel<<<1, 256, 0, stream>>>(blkSums);
        scan_add_kernel<<<SCAN_NB, 256, 0, stream>>>(offsets, blkSums, cursor);
        fill_kernel<<<(N_EDGES + 255) / 256, 256, 0, stream>>>(src, dst, edge_weight,
                                                               mu1, is1, mu2, is2,
                                                               cursor, csr);
        gemm1_kernel<<<N_NODES / 16, 256, 0, stream>>>(features, W1, h1);
        agg1_gemm2_kernel<<<N_NODES / 4, 256, 0, stream>>>(h1, offsets, csr, b1, W2, h2);
        agg2_kernel<<<(N_NODES + 3) / 4, 256, 0, stream>>>(h2, offsets, csr, b2, out);
    }
}

// Round 8
// 304.187 us; speedup vs baseline: 4.0834x; 4.0834x over previous
//
#include <hip/hip_runtime.h>
#include <hip/hip_fp16.h>
#include <math.h>

#define N_NODES 50000
#define N_EDGES 800000
#define IN_FEATS 128
#define N_HIDDEN 64
#define OUT_FEATS 40
#define DIM 8
#define SCAN_NB ((N_NODES + 255) / 256)       // 196
#define EDGE_BLOCKS 1024
#define GT_TILES ((N_NODES + 63) / 64)        // 782 node tiles of 64

// ---------------- wave-wide inclusive scan (64 lanes) ----------------
__device__ __forceinline__ int wave_incl_scan(int x, int lane) {
#pragma unroll
    for (int off = 1; off < 64; off <<= 1) {
        int v = __shfl_up(x, off, 64);
        if (lane >= off) x += v;
    }
    return x;
}

// ============================================================================
// Combo: blocks [0, EDGE_BLOCKS) do edge pre-pass (histogram + gaussian pack);
//        blocks [EDGE_BLOCKS, +GT_TILES) do gemm1 (h1 = features @ W1 -> fp16).
// The two halves are data-independent.
// ============================================================================
__global__ __launch_bounds__(256) void combo_kernel(
    const float* __restrict__ features, const float* __restrict__ W1,
    const int* __restrict__ src, const int* __restrict__ dst,
    const float* __restrict__ ew,
    const float* __restrict__ mu1, const float* __restrict__ is1,
    const float* __restrict__ mu2, const float* __restrict__ is2,
    int* __restrict__ counts, int2* __restrict__ tmp,
    __half* __restrict__ h1)
{
    const int tid = threadIdx.x;
    __shared__ float xs[64][132];   // 33 KB; stride 132: float4-aligned, 2-way banks (free)

    if (blockIdx.x < EDGE_BLOCKS) {
        // ---- edge pre-pass: in-degree histogram + packed {src, (g1,g2):half2} ----
        for (int e = blockIdx.x * 256 + tid; e < N_EDGES; e += EDGE_BLOCKS * 256) {
            atomicAdd(&counts[dst[e]], 1);
            float s1 = 0.f, s2 = 0.f;
#pragma unroll
            for (int d = 0; d < DIM; ++d) {
                float v = ew[e * DIM + d];
                float d1 = v - mu1[d]; float a1 = is1[d];
                float d2 = v - mu2[d]; float a2 = is2[d];
                s1 += d1 * d1 * a1 * a1;
                s2 += d2 * d2 * a2 * a2;
            }
            __half2 g = __floats2half2_rn(expf(-0.5f * s1), expf(-0.5f * s2));
            int2 rec;
            rec.x = src[e];
            rec.y = *reinterpret_cast<int*>(&g);
            tmp[e] = rec;
        }
        return;
    }

    // ---- gemm1 tile: 64 nodes per block; wave = 16 nodes; lane = 4 nodes x 4 feats ----
    int tile = blockIdx.x - EDGE_BLOCKS;
    int nodeBase = tile * 64;
    // stage 64 rows x 128 cols fp32 (float4 loads, zero-pad OOB rows)
    for (int i = tid; i < 64 * 32; i += 256) {
        int row = i >> 5, c4 = i & 31;
        int n = nodeBase + row;
        float4 v = make_float4(0.f, 0.f, 0.f, 0.f);
        if (n < N_NODES) v = ((const float4*)features)[(size_t)n * 32 + c4];
        *(float4*)&xs[row][c4 * 4] = v;
    }
    __syncthreads();

    int lane = tid & 63, wid = tid >> 6;
    int f4 = lane & 15;            // output feature quad
    int nq = lane >> 4;            // node quad index within the wave's 16 nodes
    int rowBase = wid * 16 + nq * 4;
    const float4* W4 = (const float4*)W1;

    float4 acc0 = make_float4(0.f,0.f,0.f,0.f), acc1 = acc0, acc2 = acc0, acc3 = acc0;
    for (int k = 0; k < IN_FEATS; k += 4) {
        float4 x0 = *(const float4*)&xs[rowBase + 0][k];
        float4 x1 = *(const float4*)&xs[rowBase + 1][k];
        float4 x2 = *(const float4*)&xs[rowBase + 2][k];
        float4 x3 = *(const float4*)&xs[rowBase + 3][k];
        float4 w0 = W4[(k + 0) * 16 + f4];
        float4 w1 = W4[(k + 1) * 16 + f4];
        float4 w2 = W4[(k + 2) * 16 + f4];
        float4 w3 = W4[(k + 3) * 16 + f4];
#define FMA4(A, XV) \
        A.x += XV.x * w0.x + XV.y * w1.x + XV.z * w2.x + XV.w * w3.x; \
        A.y += XV.x * w0.y + XV.y * w1.y + XV.z * w2.y + XV.w * w3.y; \
        A.z += XV.x * w0.z + XV.y * w1.z + XV.z * w2.z + XV.w * w3.z; \
        A.w += XV.x * w0.w + XV.y * w1.w + XV.z * w2.w + XV.w * w3.w;
        FMA4(acc0, x0) FMA4(acc1, x1) FMA4(acc2, x2) FMA4(acc3, x3)
#undef FMA4
    }
#define STORE(A, I) { \
        int n = nodeBase + rowBase + I; \
        if (n < N_NODES) { \
            __half2 lo = __floats2half2_rn(A.x, A.y); \
            __half2 hi = __floats2half2_rn(A.z, A.w); \
            uint2 pk; pk.x = *reinterpret_cast<unsigned*>(&lo); \
            pk.y = *reinterpret_cast<unsigned*>(&hi); \
            *reinterpret_cast<uint2*>(&h1[(size_t)n * N_HIDDEN + 4 * f4]) = pk; \
        } }
    STORE(acc0, 0) STORE(acc1, 1) STORE(acc2, 2) STORE(acc3, 3)
#undef STORE
}

// ============================================================================
// Single-dispatch decoupled-lookback scan over counts -> offsets + cursor.
// partials[b] = (sum<<2)|state; state 0=empty, 1=aggregate, 2=inclusive.
// ============================================================================
__global__ __launch_bounds__(256) void scan_kernel(const int* __restrict__ counts,
                                                   int* __restrict__ offsets,
                                                   int* __restrict__ cursor,
                                                   int* __restrict__ partials) {
    const int tid = threadIdx.x, bid = blockIdx.x;
    int i = bid * 256 + tid;
    int lane = tid & 63, wid = tid >> 6;
    int x = (i < N_NODES) ? counts[i] : 0;
    int incl = wave_incl_scan(x, lane);
    __shared__ int wsum[4];
    __shared__ int sExc, sTot;
    if (lane == 63) wsum[wid] = incl;
    __syncthreads();
    int base = 0;
#pragma unroll
    for (int w = 0; w < 4; ++w)
        if (w < wid) base += wsum[w];
    int lexcl = base + incl - x;
    if (tid == 255) sTot = base + incl;
    __syncthreads();
    if (tid == 0) {
        int T = sTot;
        if (bid == 0) {
            __hip_atomic_store(&partials[0], (T << 2) | 2,
                               __ATOMIC_RELAXED, __HIP_MEMORY_SCOPE_AGENT);
            sExc = 0;
        } else {
            __hip_atomic_store(&partials[bid], (T << 2) | 1,
                               __ATOMIC_RELAXED, __HIP_MEMORY_SCOPE_AGENT);
            int sum = 0, pb = bid - 1;
            while (true) {
                int v = __hip_atomic_load(&partials[pb],
                                          __ATOMIC_RELAXED, __HIP_MEMORY_SCOPE_AGENT);
                if (v == 0) continue;
                sum += v >> 2;
                if ((v & 3) == 2) break;
                --pb;
            }
            __hip_atomic_store(&partials[bid], ((sum + T) << 2) | 2,
                               __ATOMIC_RELAXED, __HIP_MEMORY_SCOPE_AGENT);
            sExc = sum;
        }
    }
    __syncthreads();
    int E = sExc;
    if (i < N_NODES) {
        int v = E + lexcl;
        offsets[i] = v;
        cursor[i]  = v;
    }
    if (bid == SCAN_NB - 1 && tid == 0) offsets[N_NODES] = N_EDGES;
}

// ---------------- fill: scatter packed records into dst-CSR slots ----------------
__global__ void fill_kernel(const int* __restrict__ dst, const int2* __restrict__ tmp,
                            int* __restrict__ cursor, int2* __restrict__ csr) {
    int e = blockIdx.x * blockDim.x + threadIdx.x;
    if (e >= N_EDGES) return;
    int pos = atomicAdd(&cursor[dst[e]], 1);
    csr[pos] = tmp[e];
}

// ---------------- agg1 + gemm2 fused: h2[n] = (sum g1*h1[src] + b1) @ W2 -> fp16 ----------------
__global__ __launch_bounds__(256) void agg1_gemm2_kernel(const __half* __restrict__ h,
                                                         const int* __restrict__ offsets,
                                                         const int2* __restrict__ csr,
                                                         const float* __restrict__ b,
                                                         const float* __restrict__ W2,
                                                         __half* __restrict__ h2) {
    __shared__ float xs[4 * N_HIDDEN];
    int wid = threadIdx.x >> 6;
    int t   = threadIdx.x & 63;
    int n   = blockIdx.x * 4 + wid;
    int beg = offsets[n], end = offsets[n + 1];
    float a0 = 0.f, a1 = 0.f, a2 = 0.f, a3 = 0.f;
    int j = beg;
    for (; j + 8 <= end; j += 8) {
        int2 c0 = csr[j + 0], c1 = csr[j + 1], c2 = csr[j + 2], c3 = csr[j + 3];
        int2 c4 = csr[j + 4], c5 = csr[j + 5], c6 = csr[j + 6], c7 = csr[j + 7];
        float v0 = __half2float(h[(size_t)c0.x * N_HIDDEN + t]);
        float v1 = __half2float(h[(size_t)c1.x * N_HIDDEN + t]);
        float v2 = __half2float(h[(size_t)c2.x * N_HIDDEN + t]);
        float v3 = __half2float(h[(size_t)c3.x * N_HIDDEN + t]);
        float v4 = __half2float(h[(size_t)c4.x * N_HIDDEN + t]);
        float v5 = __half2float(h[(size_t)c5.x * N_HIDDEN + t]);
        float v6 = __half2float(h[(size_t)c6.x * N_HIDDEN + t]);
        float v7 = __half2float(h[(size_t)c7.x * N_HIDDEN + t]);
        a0 += v0 * __low2float(*reinterpret_cast<__half2*>(&c0.y));
        a1 += v1 * __low2float(*reinterpret_cast<__half2*>(&c1.y));
        a2 += v2 * __low2float(*reinterpret_cast<__half2*>(&c2.y));
        a3 += v3 * __low2float(*reinterpret_cast<__half2*>(&c3.y));
        a0 += v4 * __low2float(*reinterpret_cast<__half2*>(&c4.y));
        a1 += v5 * __low2float(*reinterpret_cast<__half2*>(&c5.y));
        a2 += v6 * __low2float(*reinterpret_cast<__half2*>(&c6.y));
        a3 += v7 * __low2float(*reinterpret_cast<__half2*>(&c7.y));
    }
    for (; j < end; ++j) {
        int2 c = csr[j];
        a0 += __half2float(h[(size_t)c.x * N_HIDDEN + t]) *
              __low2float(*reinterpret_cast<__half2*>(&c.y));
    }
    float x = (a0 + a1) + (a2 + a3) + b[t];
    xs[wid * N_HIDDEN + t] = x;   // wave-private region: no barrier needed
    if (t < OUT_FEATS) {
        const float* xr = &xs[wid * N_HIDDEN];
        float acc = 0.f;
#pragma unroll
        for (int k = 0; k < N_HIDDEN; ++k)
            acc += xr[k] * W2[k * OUT_FEATS + t];
        h2[(size_t)n * OUT_FEATS + t] = __float2half(acc);
    }
}

// ---------------- agg layer 2 + b2 + log_softmax fused ----------------
__global__ __launch_bounds__(256) void agg2_kernel(const __half* __restrict__ h,
                                                   const int* __restrict__ offsets,
                                                   const int2* __restrict__ csr,
                                                   const float* __restrict__ b,
                                                   float* __restrict__ out) {
    int n = blockIdx.x * 4 + (threadIdx.x >> 6);
    int t = threadIdx.x & 63;
    if (n >= N_NODES) return;
    int tc = (t < OUT_FEATS) ? t : (OUT_FEATS - 1);
    int beg = offsets[n], end = offsets[n + 1];
    float a0 = 0.f, a1 = 0.f, a2 = 0.f, a3 = 0.f;
    int j = beg;
    for (; j + 8 <= end; j += 8) {
        int2 c0 = csr[j + 0], c1 = csr[j + 1], c2 = csr[j + 2], c3 = csr[j + 3];
        int2 c4 = csr[j + 4], c5 = csr[j + 5], c6 = csr[j + 6], c7 = csr[j + 7];
        float v0 = __half2float(h[(size_t)c0.x * OUT_FEATS + tc]);
        float v1 = __half2float(h[(size_t)c1.x * OUT_FEATS + tc]);
        float v2 = __half2float(h[(size_t)c2.x * OUT_FEATS + tc]);
        float v3 = __half2float(h[(size_t)c3.x * OUT_FEATS + tc]);
        float v4 = __half2float(h[(size_t)c4.x * OUT_FEATS + tc]);
        float v5 = __half2float(h[(size_t)c5.x * OUT_FEATS + tc]);
        float v6 = __half2float(h[(size_t)c6.x * OUT_FEATS + tc]);
        float v7 = __half2float(h[(size_t)c7.x * OUT_FEATS + tc]);
        a0 += v0 * __high2float(*reinterpret_cast<__half2*>(&c0.y));
        a1 += v1 * __high2float(*reinterpret_cast<__half2*>(&c1.y));
        a2 += v2 * __high2float(*reinterpret_cast<__half2*>(&c2.y));
        a3 += v3 * __high2float(*reinterpret_cast<__half2*>(&c3.y));
        a0 += v4 * __high2float(*reinterpret_cast<__half2*>(&c4.y));
        a1 += v5 * __high2float(*reinterpret_cast<__half2*>(&c5.y));
        a2 += v6 * __high2float(*reinterpret_cast<__half2*>(&c6.y));
        a3 += v7 * __high2float(*reinterpret_cast<__half2*>(&c7.y));
    }
    for (; j < end; ++j) {
        int2 c = csr[j];
        a0 += __half2float(h[(size_t)c.x * OUT_FEATS + tc]) *
              __high2float(*reinterpret_cast<__half2*>(&c.y));
    }
    float acc = (a0 + a1) + (a2 + a3);
    float v = (t < OUT_FEATS) ? acc + b[t] : -INFINITY;
    float m = v;
#pragma unroll
    for (int off = 32; off; off >>= 1)
        m = fmaxf(m, __shfl_xor(m, off, 64));
    float ex = (t < OUT_FEATS) ? expf(v - m) : 0.f;
    float s = ex;
#pragma unroll
    for (int off = 32; off; off >>= 1)
        s += __shfl_xor(s, off, 64);
    if (t < OUT_FEATS)
        out[n * OUT_FEATS + t] = v - m - logf(s);
}

extern "C" void kernel_launch(void* const* d_in, const int* in_sizes, int n_in,
                              void* d_out, int out_size, void* d_ws, size_t ws_size,
                              hipStream_t stream) {
    const float* features    = (const float*)d_in[0];
    const float* edge_weight = (const float*)d_in[1];
    const int*   src         = (const int*)d_in[2];
    const int*   dst         = (const int*)d_in[3];
    const float* W1          = (const float*)d_in[4];
    const float* b1          = (const float*)d_in[5];
    const float* mu1         = (const float*)d_in[6];
    const float* is1         = (const float*)d_in[7];
    const float* W2          = (const float*)d_in[8];
    const float* b2          = (const float*)d_in[9];
    const float* mu2         = (const float*)d_in[10];
    const float* is2         = (const float*)d_in[11];
    float* out = (float*)d_out;

    // Workspace: csr int2[800k] | tmp int2[800k] | h1 half[3.2M] | h2 half[2M]
    //            | counts[50k] | partials[256] | cursor[50k] | offsets[50k+1]
    int2*   csr     = (int2*)d_ws;
    int2*   tmp     = csr + N_EDGES;
    __half* h1      = (__half*)(tmp + N_EDGES);
    __half* h2      = h1 + (size_t)N_NODES * N_HIDDEN;
    int*    counts  = (int*)(h2 + (size_t)N_NODES * OUT_FEATS);
    int*    partials= counts + N_NODES;          // 256 slots (196 used)
    int*    cursor  = partials + 256;
    int*    offsets = cursor + N_NODES;

    // one memset covers counts + partials (contiguous)
    hipMemsetAsync(counts, 0, (N_NODES + 256) * sizeof(int), stream);

    combo_kernel<<<EDGE_BLOCKS + GT_TILES, 256, 0, stream>>>(
        features, W1, src, dst, edge_weight, mu1, is1, mu2, is2, counts, tmp, h1);

    scan_kernel<<<SCAN_NB, 256, 0, stream>>>(counts, offsets, cursor, partials);

    fill_kernel<<<(N_EDGES + 255) / 256, 256, 0, stream>>>(dst, tmp, cursor, csr);

    agg1_gemm2_kernel<<<N_NODES / 4, 256, 0, stream>>>(h1, offsets, csr, b1, W2, h2);

    agg2_kernel<<<(N_NODES + 3) / 4, 256, 0, stream>>>(h2, offsets, csr, b2, out);
}

// Round 9
// 303.987 us; speedup vs baseline: 4.0861x; 1.0007x over previous
//
#include <hip/hip_runtime.h>
#include <hip/hip_fp16.h>
#include <math.h>

#define N_NODES 50000
#define N_EDGES 800000
#define IN_FEATS 128
#define N_HIDDEN 64
#define OUT_FEATS 40
#define DIM 8
#define SCAN_NB ((N_NODES + 255) / 256)       // 196
#define EDGE_BLOCKS 1024
#define GT_TILES ((N_NODES + 63) / 64)        // 782 node tiles of 64

// ---------------- wave-wide inclusive scan (64 lanes) ----------------
__device__ __forceinline__ int wave_incl_scan(int x, int lane) {
#pragma unroll
    for (int off = 1; off < 64; off <<= 1) {
        int v = __shfl_up(x, off, 64);
        if (lane >= off) x += v;
    }
    return x;
}

// ============================================================================
// Combo: blocks [0, EDGE_BLOCKS) do edge pre-pass (histogram + gaussian pack);
//        blocks [EDGE_BLOCKS, +GT_TILES) do gemm1 (h1 = features @ W1 -> fp16).
// LDS staging is fp16 (17.4 KB) -> 8 blocks/CU, full wave occupancy.
// ============================================================================
__global__ __launch_bounds__(256) void combo_kernel(
    const float* __restrict__ features, const float* __restrict__ W1,
    const int* __restrict__ src, const int* __restrict__ dst,
    const float* __restrict__ ew,
    const float* __restrict__ mu1, const float* __restrict__ is1,
    const float* __restrict__ mu2, const float* __restrict__ is2,
    int* __restrict__ counts, int2* __restrict__ tmp,
    __half* __restrict__ h1)
{
    const int tid = threadIdx.x;
    // stride 136 halfs = 272 B: 8B-aligned rows; row delta of 4 rows = 16 banks
    // -> only 2-way bank aliasing between nq pairs (free per m136)
    __shared__ __half xs[64][136];   // 17408 B

    if (blockIdx.x < EDGE_BLOCKS) {
        // ---- edge pre-pass: in-degree histogram + packed {src, (g1,g2):half2} ----
        for (int e = blockIdx.x * 256 + tid; e < N_EDGES; e += EDGE_BLOCKS * 256) {
            atomicAdd(&counts[dst[e]], 1);
            float s1 = 0.f, s2 = 0.f;
#pragma unroll
            for (int d = 0; d < DIM; ++d) {
                float v = ew[e * DIM + d];
                float d1 = v - mu1[d]; float a1 = is1[d];
                float d2 = v - mu2[d]; float a2 = is2[d];
                s1 += d1 * d1 * a1 * a1;
                s2 += d2 * d2 * a2 * a2;
            }
            __half2 g = __floats2half2_rn(expf(-0.5f * s1), expf(-0.5f * s2));
            int2 rec;
            rec.x = src[e];
            rec.y = *reinterpret_cast<int*>(&g);
            tmp[e] = rec;
        }
        return;
    }

    // ---- gemm1 tile: 64 nodes per block; wave = 16 nodes; lane = 4 nodes x 4 feats ----
    int tile = blockIdx.x - EDGE_BLOCKS;
    int nodeBase = tile * 64;
    // stage 64 rows x 128 cols as fp16 (float4 global loads, packed 8B LDS stores)
    for (int i = tid; i < 64 * 32; i += 256) {
        int row = i >> 5, c4 = i & 31;
        int n = nodeBase + row;
        float4 v = make_float4(0.f, 0.f, 0.f, 0.f);
        if (n < N_NODES) v = ((const float4*)features)[(size_t)n * 32 + c4];
        __half2 h01 = __floats2half2_rn(v.x, v.y);
        __half2 h23 = __floats2half2_rn(v.z, v.w);
        uint2 pk;
        pk.x = *reinterpret_cast<unsigned*>(&h01);
        pk.y = *reinterpret_cast<unsigned*>(&h23);
        *reinterpret_cast<uint2*>(&xs[row][c4 * 4]) = pk;
    }
    __syncthreads();

    int lane = tid & 63, wid = tid >> 6;
    int f4 = lane & 15;            // output feature quad
    int nq = lane >> 4;            // node quad index within the wave's 16 nodes
    int rowBase = wid * 16 + nq * 4;
    const float4* W4 = (const float4*)W1;

    float4 acc0 = make_float4(0.f,0.f,0.f,0.f), acc1 = acc0, acc2 = acc0, acc3 = acc0;
    for (int k = 0; k < IN_FEATS; k += 4) {
        // 8B LDS reads, unpack to float4
#define LOADX(R) ({ \
        uint2 q = *reinterpret_cast<const uint2*>(&xs[R][k]); \
        float2 lo = __half22float2(*reinterpret_cast<__half2*>(&q.x)); \
        float2 hi = __half22float2(*reinterpret_cast<__half2*>(&q.y)); \
        make_float4(lo.x, lo.y, hi.x, hi.y); })
        float4 x0 = LOADX(rowBase + 0);
        float4 x1 = LOADX(rowBase + 1);
        float4 x2 = LOADX(rowBase + 2);
        float4 x3 = LOADX(rowBase + 3);
#undef LOADX
        float4 w0 = W4[(k + 0) * 16 + f4];
        float4 w1 = W4[(k + 1) * 16 + f4];
        float4 w2 = W4[(k + 2) * 16 + f4];
        float4 w3 = W4[(k + 3) * 16 + f4];
#define FMA4(A, XV) \
        A.x += XV.x * w0.x + XV.y * w1.x + XV.z * w2.x + XV.w * w3.x; \
        A.y += XV.x * w0.y + XV.y * w1.y + XV.z * w2.y + XV.w * w3.y; \
        A.z += XV.x * w0.z + XV.y * w1.z + XV.z * w2.z + XV.w * w3.z; \
        A.w += XV.x * w0.w + XV.y * w1.w + XV.z * w2.w + XV.w * w3.w;
        FMA4(acc0, x0) FMA4(acc1, x1) FMA4(acc2, x2) FMA4(acc3, x3)
#undef FMA4
    }
#define STORE(A, I) { \
        int n = nodeBase + rowBase + I; \
        if (n < N_NODES) { \
            __half2 lo = __floats2half2_rn(A.x, A.y); \
            __half2 hi = __floats2half2_rn(A.z, A.w); \
            uint2 pk; pk.x = *reinterpret_cast<unsigned*>(&lo); \
            pk.y = *reinterpret_cast<unsigned*>(&hi); \
            *reinterpret_cast<uint2*>(&h1[(size_t)n * N_HIDDEN + 4 * f4]) = pk; \
        } }
    STORE(acc0, 0) STORE(acc1, 1) STORE(acc2, 2) STORE(acc3, 3)
#undef STORE
}

// ============================================================================
// Single-dispatch decoupled-lookback scan over counts -> offsets + cursor.
// partials[b] = (sum<<2)|state; state 0=empty, 1=aggregate, 2=inclusive.
// ============================================================================
__global__ __launch_bounds__(256) void scan_kernel(const int* __restrict__ counts,
                                                   int* __restrict__ offsets,
                                                   int* __restrict__ cursor,
                                                   int* __restrict__ partials) {
    const int tid = threadIdx.x, bid = blockIdx.x;
    int i = bid * 256 + tid;
    int lane = tid & 63, wid = tid >> 6;
    int x = (i < N_NODES) ? counts[i] : 0;
    int incl = wave_incl_scan(x, lane);
    __shared__ int wsum[4];
    __shared__ int sExc, sTot;
    if (lane == 63) wsum[wid] = incl;
    __syncthreads();
    int base = 0;
#pragma unroll
    for (int w = 0; w < 4; ++w)
        if (w < wid) base += wsum[w];
    int lexcl = base + incl - x;
    if (tid == 255) sTot = base + incl;
    __syncthreads();
    if (tid == 0) {
        int T = sTot;
        if (bid == 0) {
            __hip_atomic_store(&partials[0], (T << 2) | 2,
                               __ATOMIC_RELAXED, __HIP_MEMORY_SCOPE_AGENT);
            sExc = 0;
        } else {
            __hip_atomic_store(&partials[bid], (T << 2) | 1,
                               __ATOMIC_RELAXED, __HIP_MEMORY_SCOPE_AGENT);
            int sum = 0, pb = bid - 1;
            while (true) {
                int v = __hip_atomic_load(&partials[pb],
                                          __ATOMIC_RELAXED, __HIP_MEMORY_SCOPE_AGENT);
                if (v == 0) continue;
                sum += v >> 2;
                if ((v & 3) == 2) break;
                --pb;
            }
            __hip_atomic_store(&partials[bid], ((sum + T) << 2) | 2,
                               __ATOMIC_RELAXED, __HIP_MEMORY_SCOPE_AGENT);
            sExc = sum;
        }
    }
    __syncthreads();
    int E = sExc;
    if (i < N_NODES) {
        int v = E + lexcl;
        offsets[i] = v;
        cursor[i]  = v;
    }
    if (bid == SCAN_NB - 1 && tid == 0) offsets[N_NODES] = N_EDGES;
}

// ---------------- fill: scatter packed records into dst-CSR slots ----------------
__global__ void fill_kernel(const int* __restrict__ dst, const int2* __restrict__ tmp,
                            int* __restrict__ cursor, int2* __restrict__ csr) {
    int e = blockIdx.x * blockDim.x + threadIdx.x;
    if (e >= N_EDGES) return;
    int pos = atomicAdd(&cursor[dst[e]], 1);
    csr[pos] = tmp[e];
}

// ---------------- agg1 + gemm2 fused: h2[n] = (sum g1*h1[src] + b1) @ W2 -> fp16 ----------------
__global__ __launch_bounds__(256) void agg1_gemm2_kernel(const __half* __restrict__ h,
                                                         const int* __restrict__ offsets,
                                                         const int2* __restrict__ csr,
                                                         const float* __restrict__ b,
                                                         const float* __restrict__ W2,
                                                         __half* __restrict__ h2) {
    __shared__ float xs[4 * N_HIDDEN];
    int wid = threadIdx.x >> 6;
    int t   = threadIdx.x & 63;
    int n   = blockIdx.x * 4 + wid;
    int beg = offsets[n], end = offsets[n + 1];
    float a0 = 0.f, a1 = 0.f, a2 = 0.f, a3 = 0.f;
    int j = beg;
    for (; j + 8 <= end; j += 8) {
        int2 c0 = csr[j + 0], c1 = csr[j + 1], c2 = csr[j + 2], c3 = csr[j + 3];
        int2 c4 = csr[j + 4], c5 = csr[j + 5], c6 = csr[j + 6], c7 = csr[j + 7];
        float v0 = __half2float(h[(size_t)c0.x * N_HIDDEN + t]);
        float v1 = __half2float(h[(size_t)c1.x * N_HIDDEN + t]);
        float v2 = __half2float(h[(size_t)c2.x * N_HIDDEN + t]);
        float v3 = __half2float(h[(size_t)c3.x * N_HIDDEN + t]);
        float v4 = __half2float(h[(size_t)c4.x * N_HIDDEN + t]);
        float v5 = __half2float(h[(size_t)c5.x * N_HIDDEN + t]);
        float v6 = __half2float(h[(size_t)c6.x * N_HIDDEN + t]);
        float v7 = __half2float(h[(size_t)c7.x * N_HIDDEN + t]);
        a0 += v0 * __low2float(*reinterpret_cast<__half2*>(&c0.y));
        a1 += v1 * __low2float(*reinterpret_cast<__half2*>(&c1.y));
        a2 += v2 * __low2float(*reinterpret_cast<__half2*>(&c2.y));
        a3 += v3 * __low2float(*reinterpret_cast<__half2*>(&c3.y));
        a0 += v4 * __low2float(*reinterpret_cast<__half2*>(&c4.y));
        a1 += v5 * __low2float(*reinterpret_cast<__half2*>(&c5.y));
        a2 += v6 * __low2float(*reinterpret_cast<__half2*>(&c6.y));
        a3 += v7 * __low2float(*reinterpret_cast<__half2*>(&c7.y));
    }
    for (; j < end; ++j) {
        int2 c = csr[j];
        a0 += __half2float(h[(size_t)c.x * N_HIDDEN + t]) *
              __low2float(*reinterpret_cast<__half2*>(&c.y));
    }
    float x = (a0 + a1) + (a2 + a3) + b[t];
    xs[wid * N_HIDDEN + t] = x;   // wave-private region: no barrier needed
    if (t < OUT_FEATS) {
        const float* xr = &xs[wid * N_HIDDEN];
        float acc = 0.f;
#pragma unroll
        for (int k = 0; k < N_HIDDEN; ++k)
            acc += xr[k] * W2[k * OUT_FEATS + t];
        h2[(size_t)n * OUT_FEATS + t] = __float2half(acc);
    }
}

// ---------------- agg layer 2 + b2 + log_softmax fused ----------------
__global__ __launch_bounds__(256) void agg2_kernel(const __half* __restrict__ h,
                                                   const int* __restrict__ offsets,
                                                   const int2* __restrict__ csr,
                                                   const float* __restrict__ b,
                                                   float* __restrict__ out) {
    int n = blockIdx.x * 4 + (threadIdx.x >> 6);
    int t = threadIdx.x & 63;
    if (n >= N_NODES) return;
    int tc = (t < OUT_FEATS) ? t : (OUT_FEATS - 1);
    int beg = offsets[n], end = offsets[n + 1];
    float a0 = 0.f, a1 = 0.f, a2 = 0.f, a3 = 0.f;
    int j = beg;
    for (; j + 8 <= end; j += 8) {
        int2 c0 = csr[j + 0], c1 = csr[j + 1], c2 = csr[j + 2], c3 = csr[j + 3];
        int2 c4 = csr[j + 4], c5 = csr[j + 5], c6 = csr[j + 6], c7 = csr[j + 7];
        float v0 = __half2float(h[(size_t)c0.x * OUT_FEATS + tc]);
        float v1 = __half2float(h[(size_t)c1.x * OUT_FEATS + tc]);
        float v2 = __half2float(h[(size_t)c2.x * OUT_FEATS + tc]);
        float v3 = __half2float(h[(size_t)c3.x * OUT_FEATS + tc]);
        float v4 = __half2float(h[(size_t)c4.x * OUT_FEATS + tc]);
        float v5 = __half2float(h[(size_t)c5.x * OUT_FEATS + tc]);
        float v6 = __half2float(h[(size_t)c6.x * OUT_FEATS + tc]);
        float v7 = __half2float(h[(size_t)c7.x * OUT_FEATS + tc]);
        a0 += v0 * __high2float(*reinterpret_cast<__half2*>(&c0.y));
        a1 += v1 * __high2float(*reinterpret_cast<__half2*>(&c1.y));
        a2 += v2 * __high2float(*reinterpret_cast<__half2*>(&c2.y));
        a3 += v3 * __high2float(*reinterpret_cast<__half2*>(&c3.y));
        a0 += v4 * __high2float(*reinterpret_cast<__half2*>(&c4.y));
        a1 += v5 * __high2float(*reinterpret_cast<__half2*>(&c5.y));
        a2 += v6 * __high2float(*reinterpret_cast<__half2*>(&c6.y));
        a3 += v7 * __high2float(*reinterpret_cast<__half2*>(&c7.y));
    }
    for (; j < end; ++j) {
        int2 c = csr[j];
        a0 += __half2float(h[(size_t)c.x * OUT_FEATS + tc]) *
              __high2float(*reinterpret_cast<__half2*>(&c.y));
    }
    float acc = (a0 + a1) + (a2 + a3);
    float v = (t < OUT_FEATS) ? acc + b[t] : -INFINITY;
    float m = v;
#pragma unroll
    for (int off = 32; off; off >>= 1)
        m = fmaxf(m, __shfl_xor(m, off, 64));
    float ex = (t < OUT_FEATS) ? expf(v - m) : 0.f;
    float s = ex;
#pragma unroll
    for (int off = 32; off; off >>= 1)
        s += __shfl_xor(s, off, 64);
    if (t < OUT_FEATS)
        out[n * OUT_FEATS + t] = v - m - logf(s);
}

extern "C" void kernel_launch(void* const* d_in, const int* in_sizes, int n_in,
                              void* d_out, int out_size, void* d_ws, size_t ws_size,
                              hipStream_t stream) {
    const float* features    = (const float*)d_in[0];
    const float* edge_weight = (const float*)d_in[1];
    const int*   src         = (const int*)d_in[2];
    const int*   dst         = (const int*)d_in[3];
    const float* W1          = (const float*)d_in[4];
    const float* b1          = (const float*)d_in[5];
    const float* mu1         = (const float*)d_in[6];
    const float* is1         = (const float*)d_in[7];
    const float* W2          = (const float*)d_in[8];
    const float* b2          = (const float*)d_in[9];
    const float* mu2         = (const float*)d_in[10];
    const float* is2         = (const float*)d_in[11];
    float* out = (float*)d_out;

    // Workspace: csr int2[800k] | tmp int2[800k] | h1 half[3.2M] | h2 half[2M]
    //            | counts[50k] | partials[256] | cursor[50k] | offsets[50k+1]
    int2*   csr     = (int2*)d_ws;
    int2*   tmp     = csr + N_EDGES;
    __half* h1      = (__half*)(tmp + N_EDGES);
    __half* h2      = h1 + (size_t)N_NODES * N_HIDDEN;
    int*    counts  = (int*)(h2 + (size_t)N_NODES * OUT_FEATS);
    int*    partials= counts + N_NODES;          // 256 slots (196 used)
    int*    cursor  = partials + 256;
    int*    offsets = cursor + N_NODES;

    // one memset covers counts + partials (contiguous)
    hipMemsetAsync(counts, 0, (N_NODES + 256) * sizeof(int), stream);

    combo_kernel<<<EDGE_BLOCKS + GT_TILES, 256, 0, stream>>>(
        features, W1, src, dst, edge_weight, mu1, is1, mu2, is2, counts, tmp, h1);

    scan_kernel<<<SCAN_NB, 256, 0, stream>>>(counts, offsets, cursor, partials);

    fill_kernel<<<(N_EDGES + 255) / 256, 256, 0, stream>>>(dst, tmp, cursor, csr);

    agg1_gemm2_kernel<<<N_NODES / 4, 256, 0, stream>>>(h1, offsets, csr, b1, W2, h2);

    agg2_kernel<<<(N_NODES + 3) / 4, 256, 0, stream>>>(h2, offsets, csr, b2, out);
}

// Round 10
// 293.043 us; speedup vs baseline: 4.2386x; 1.0373x over previous
//
#include <hip/hip_runtime.h>
#include <hip/hip_fp16.h>
#include <math.h>

#define N_NODES 50000
#define N_EDGES 800000
#define IN_FEATS 128
#define N_HIDDEN 64
#define OUT_FEATS 40
#define DIM 8
#define SCAN_NB ((N_NODES + 255) / 256)       // 196
#define EDGE_BLOCKS 1024
#define GT_TILES ((N_NODES + 63) / 64)        // 782 node tiles of 64

typedef _Float16 half8 __attribute__((ext_vector_type(8)));
typedef float floatx4 __attribute__((ext_vector_type(4)));

// ---------------- wave-wide inclusive scan (64 lanes) ----------------
__device__ __forceinline__ int wave_incl_scan(int x, int lane) {
#pragma unroll
    for (int off = 1; off < 64; off <<= 1) {
        int v = __shfl_up(x, off, 64);
        if (lane >= off) x += v;
    }
    return x;
}

// ============================================================================
// Combo: blocks [0, EDGE_BLOCKS) do edge pre-pass (histogram + gaussian pack);
//        blocks [EDGE_BLOCKS, +GT_TILES) do gemm1 via MFMA (h1 = X @ W1 -> fp16).
// ============================================================================
__global__ __launch_bounds__(256) void combo_kernel(
    const float* __restrict__ features, const float* __restrict__ W1,
    const int* __restrict__ src, const int* __restrict__ dst,
    const float* __restrict__ ew,
    const float* __restrict__ mu1, const float* __restrict__ is1,
    const float* __restrict__ mu2, const float* __restrict__ is2,
    int* __restrict__ counts, int2* __restrict__ tmp,
    __half* __restrict__ h1)
{
    const int tid = threadIdx.x;
    // row stride 136 halfs = 272 B (16B-aligned, bank offset 4/row -> <=2-way, free)
    __shared__ __align__(16) __half XT[64][136];   // features tile [node][k] fp16
    __shared__ __align__(16) __half WT[64][136];   // W1 transposed [n][k]  fp16

    if (blockIdx.x < EDGE_BLOCKS) {
        // ---- edge pre-pass: in-degree histogram + packed {src, (g1,g2):half2} ----
        for (int e = blockIdx.x * 256 + tid; e < N_EDGES; e += EDGE_BLOCKS * 256) {
            atomicAdd(&counts[dst[e]], 1);
            float s1 = 0.f, s2 = 0.f;
#pragma unroll
            for (int d = 0; d < DIM; ++d) {
                float v = ew[e * DIM + d];
                float d1 = v - mu1[d]; float a1 = is1[d];
                float d2 = v - mu2[d]; float a2 = is2[d];
                s1 += d1 * d1 * a1 * a1;
                s2 += d2 * d2 * a2 * a2;
            }
            __half2 g = __floats2half2_rn(expf(-0.5f * s1), expf(-0.5f * s2));
            int2 rec;
            rec.x = src[e];
            rec.y = *reinterpret_cast<int*>(&g);
            tmp[e] = rec;
        }
        return;
    }

    // ---- gemm1 tile: 64 nodes x 64 feats per block, MFMA 16x16x32 f16 ----
    int tile = blockIdx.x - EDGE_BLOCKS;
    int nodeBase = tile * 64;

    // stage features tile -> XT fp16 (float4 global loads, packed 8B LDS stores)
    for (int i = tid; i < 64 * 32; i += 256) {
        int row = i >> 5, c4 = i & 31;
        int n = nodeBase + row;
        float4 v = make_float4(0.f, 0.f, 0.f, 0.f);
        if (n < N_NODES) v = ((const float4*)features)[(size_t)n * 32 + c4];
        __half2 h01 = __floats2half2_rn(v.x, v.y);
        __half2 h23 = __floats2half2_rn(v.z, v.w);
        uint2 pk;
        pk.x = *reinterpret_cast<unsigned*>(&h01);
        pk.y = *reinterpret_cast<unsigned*>(&h23);
        *reinterpret_cast<uint2*>(&XT[row][c4 * 4]) = pk;
    }
    // stage W1 (fp32 [k][64], 32 KB) -> WT fp16 [n][k] (coalesced reads, scalar LDS writes)
    for (int rep = 0; rep < 32; ++rep) {
        int idx = tid + rep * 256;          // 0..8191 = k*64 + n
        int k = idx >> 6, n = idx & 63;
        WT[n][k] = __float2half(W1[idx]);
    }
    __syncthreads();

    int lane = tid & 63, w = tid >> 6;
    int m = lane & 15, quad = lane >> 4;

    floatx4 acc0 = {0.f,0.f,0.f,0.f}, acc1 = acc0, acc2 = acc0, acc3 = acc0;
#pragma unroll
    for (int kc = 0; kc < 4; ++kc) {
        half8 a = *(const half8*)&XT[w * 16 + m][kc * 32 + quad * 8];
        half8 b0 = *(const half8*)&WT[ 0 + m][kc * 32 + quad * 8];
        half8 b1 = *(const half8*)&WT[16 + m][kc * 32 + quad * 8];
        half8 b2 = *(const half8*)&WT[32 + m][kc * 32 + quad * 8];
        half8 b3 = *(const half8*)&WT[48 + m][kc * 32 + quad * 8];
        acc0 = __builtin_amdgcn_mfma_f32_16x16x32_f16(a, b0, acc0, 0, 0, 0);
        acc1 = __builtin_amdgcn_mfma_f32_16x16x32_f16(a, b1, acc1, 0, 0, 0);
        acc2 = __builtin_amdgcn_mfma_f32_16x16x32_f16(a, b2, acc2, 0, 0, 0);
        acc3 = __builtin_amdgcn_mfma_f32_16x16x32_f16(a, b3, acc3, 0, 0, 0);
    }
    // D layout: col (feat-in-tile) = lane&15 = m, row (node-in-tile) = quad*4 + reg
    int nodeRow = nodeBase + w * 16 + quad * 4;
#pragma unroll
    for (int r = 0; r < 4; ++r) {
        int n = nodeRow + r;
        if (n < N_NODES) {
            size_t base = (size_t)n * N_HIDDEN + m;
            h1[base +  0] = __float2half(acc0[r]);
            h1[base + 16] = __float2half(acc1[r]);
            h1[base + 32] = __float2half(acc2[r]);
            h1[base + 48] = __float2half(acc3[r]);
        }
    }
}

// ============================================================================
// Single-dispatch decoupled-lookback scan over counts -> offsets + cursor.
// ============================================================================
__global__ __launch_bounds__(256) void scan_kernel(const int* __restrict__ counts,
                                                   int* __restrict__ offsets,
                                                   int* __restrict__ cursor,
                                                   int* __restrict__ partials) {
    const int tid = threadIdx.x, bid = blockIdx.x;
    int i = bid * 256 + tid;
    int lane = tid & 63, wid = tid >> 6;
    int x = (i < N_NODES) ? counts[i] : 0;
    int incl = wave_incl_scan(x, lane);
    __shared__ int wsum[4];
    __shared__ int sExc, sTot;
    if (lane == 63) wsum[wid] = incl;
    __syncthreads();
    int base = 0;
#pragma unroll
    for (int w = 0; w < 4; ++w)
        if (w < wid) base += wsum[w];
    int lexcl = base + incl - x;
    if (tid == 255) sTot = base + incl;
    __syncthreads();
    if (tid == 0) {
        int T = sTot;
        if (bid == 0) {
            __hip_atomic_store(&partials[0], (T << 2) | 2,
                               __ATOMIC_RELAXED, __HIP_MEMORY_SCOPE_AGENT);
            sExc = 0;
        } else {
            __hip_atomic_store(&partials[bid], (T << 2) | 1,
                               __ATOMIC_RELAXED, __HIP_MEMORY_SCOPE_AGENT);
            int sum = 0, pb = bid - 1;
            while (true) {
                int v = __hip_atomic_load(&partials[pb],
                                          __ATOMIC_RELAXED, __HIP_MEMORY_SCOPE_AGENT);
                if (v == 0) continue;
                sum += v >> 2;
                if ((v & 3) == 2) break;
                --pb;
            }
            __hip_atomic_store(&partials[bid], ((sum + T) << 2) | 2,
                               __ATOMIC_RELAXED, __HIP_MEMORY_SCOPE_AGENT);
            sExc = sum;
        }
    }
    __syncthreads();
    int E = sExc;
    if (i < N_NODES) {
        int v = E + lexcl;
        offsets[i] = v;
        cursor[i]  = v;
    }
    if (bid == SCAN_NB - 1 && tid == 0) offsets[N_NODES] = N_EDGES;
}

// ---------------- fill: scatter packed records into dst-CSR slots ----------------
__global__ void fill_kernel(const int* __restrict__ dst, const int2* __restrict__ tmp,
                            int* __restrict__ cursor, int2* __restrict__ csr) {
    int e = blockIdx.x * blockDim.x + threadIdx.x;
    if (e >= N_EDGES) return;
    int pos = atomicAdd(&cursor[dst[e]], 1);
    csr[pos] = tmp[e];
}

// ---------------- agg1 + gemm2 fused: h2[n] = (sum g1*h1[src] + b1) @ W2 -> fp16 ----------------
__global__ __launch_bounds__(256) void agg1_gemm2_kernel(const __half* __restrict__ h,
                                                         const int* __restrict__ offsets,
                                                         const int2* __restrict__ csr,
                                                         const float* __restrict__ b,
                                                         const float* __restrict__ W2,
                                                         __half* __restrict__ h2) {
    __shared__ float xs[4 * N_HIDDEN];
    int wid = threadIdx.x >> 6;
    int t   = threadIdx.x & 63;
    int n   = blockIdx.x * 4 + wid;
    int beg = offsets[n], end = offsets[n + 1];
    float a0 = 0.f, a1 = 0.f, a2 = 0.f, a3 = 0.f;
    int j = beg;
    for (; j + 8 <= end; j += 8) {
        int2 c0 = csr[j + 0], c1 = csr[j + 1], c2 = csr[j + 2], c3 = csr[j + 3];
        int2 c4 = csr[j + 4], c5 = csr[j + 5], c6 = csr[j + 6], c7 = csr[j + 7];
        float v0 = __half2float(h[(size_t)c0.x * N_HIDDEN + t]);
        float v1 = __half2float(h[(size_t)c1.x * N_HIDDEN + t]);
        float v2 = __half2float(h[(size_t)c2.x * N_HIDDEN + t]);
        float v3 = __half2float(h[(size_t)c3.x * N_HIDDEN + t]);
        float v4 = __half2float(h[(size_t)c4.x * N_HIDDEN + t]);
        float v5 = __half2float(h[(size_t)c5.x * N_HIDDEN + t]);
        float v6 = __half2float(h[(size_t)c6.x * N_HIDDEN + t]);
        float v7 = __half2float(h[(size_t)c7.x * N_HIDDEN + t]);
        a0 += v0 * __low2float(*reinterpret_cast<__half2*>(&c0.y));
        a1 += v1 * __low2float(*reinterpret_cast<__half2*>(&c1.y));
        a2 += v2 * __low2float(*reinterpret_cast<__half2*>(&c2.y));
        a3 += v3 * __low2float(*reinterpret_cast<__half2*>(&c3.y));
        a0 += v4 * __low2float(*reinterpret_cast<__half2*>(&c4.y));
        a1 += v5 * __low2float(*reinterpret_cast<__half2*>(&c5.y));
        a2 += v6 * __low2float(*reinterpret_cast<__half2*>(&c6.y));
        a3 += v7 * __low2float(*reinterpret_cast<__half2*>(&c7.y));
    }
    for (; j < end; ++j) {
        int2 c = csr[j];
        a0 += __half2float(h[(size_t)c.x * N_HIDDEN + t]) *
              __low2float(*reinterpret_cast<__half2*>(&c.y));
    }
    float x = (a0 + a1) + (a2 + a3) + b[t];
    xs[wid * N_HIDDEN + t] = x;   // wave-private region: no barrier needed
    if (t < OUT_FEATS) {
        const float* xr = &xs[wid * N_HIDDEN];
        float acc = 0.f;
#pragma unroll
        for (int k = 0; k < N_HIDDEN; ++k)
            acc += xr[k] * W2[k * OUT_FEATS + t];
        h2[(size_t)n * OUT_FEATS + t] = __float2half(acc);
    }
}

// ---------------- agg layer 2 + b2 + log_softmax fused ----------------
__global__ __launch_bounds__(256) void agg2_kernel(const __half* __restrict__ h,
                                                   const int* __restrict__ offsets,
                                                   const int2* __restrict__ csr,
                                                   const float* __restrict__ b,
                                                   float* __restrict__ out) {
    int n = blockIdx.x * 4 + (threadIdx.x >> 6);
    int t = threadIdx.x & 63;
    if (n >= N_NODES) return;
    int tc = (t < OUT_FEATS) ? t : (OUT_FEATS - 1);
    int beg = offsets[n], end = offsets[n + 1];
    float a0 = 0.f, a1 = 0.f, a2 = 0.f, a3 = 0.f;
    int j = beg;
    for (; j + 8 <= end; j += 8) {
        int2 c0 = csr[j + 0], c1 = csr[j + 1], c2 = csr[j + 2], c3 = csr[j + 3];
        int2 c4 = csr[j + 4], c5 = csr[j + 5], c6 = csr[j + 6], c7 = csr[j + 7];
        float v0 = __half2float(h[(size_t)c0.x * OUT_FEATS + tc]);
        float v1 = __half2float(h[(size_t)c1.x * OUT_FEATS + tc]);
        float v2 = __half2float(h[(size_t)c2.x * OUT_FEATS + tc]);
        float v3 = __half2float(h[(size_t)c3.x * OUT_FEATS + tc]);
        float v4 = __half2float(h[(size_t)c4.x * OUT_FEATS + tc]);
        float v5 = __half2float(h[(size_t)c5.x * OUT_FEATS + tc]);
        float v6 = __half2float(h[(size_t)c6.x * OUT_FEATS + tc]);
        float v7 = __half2float(h[(size_t)c7.x * OUT_FEATS + tc]);
        a0 += v0 * __high2float(*reinterpret_cast<__half2*>(&c0.y));
        a1 += v1 * __high2float(*reinterpret_cast<__half2*>(&c1.y));
        a2 += v2 * __high2float(*reinterpret_cast<__half2*>(&c2.y));
        a3 += v3 * __high2float(*reinterpret_cast<__half2*>(&c3.y));
        a0 += v4 * __high2float(*reinterpret_cast<__half2*>(&c4.y));
        a1 += v5 * __high2float(*reinterpret_cast<__half2*>(&c5.y));
        a2 += v6 * __high2float(*reinterpret_cast<__half2*>(&c6.y));
        a3 += v7 * __high2float(*reinterpret_cast<__half2*>(&c7.y));
    }
    for (; j < end; ++j) {
        int2 c = csr[j];
        a0 += __half2float(h[(size_t)c.x * OUT_FEATS + tc]) *
              __high2float(*reinterpret_cast<__half2*>(&c.y));
    }
    float acc = (a0 + a1) + (a2 + a3);
    float v = (t < OUT_FEATS) ? acc + b[t] : -INFINITY;
    float m = v;
#pragma unroll
    for (int off = 32; off; off >>= 1)
        m = fmaxf(m, __shfl_xor(m, off, 64));
    float ex = (t < OUT_FEATS) ? expf(v - m) : 0.f;
    float s = ex;
#pragma unroll
    for (int off = 32; off; off >>= 1)
        s += __shfl_xor(s, off, 64);
    if (t < OUT_FEATS)
        out[n * OUT_FEATS + t] = v - m - logf(s);
}

extern "C" void kernel_launch(void* const* d_in, const int* in_sizes, int n_in,
                              void* d_out, int out_size, void* d_ws, size_t ws_size,
                              hipStream_t stream) {
    const float* features    = (const float*)d_in[0];
    const float* edge_weight = (const float*)d_in[1];
    const int*   src         = (const int*)d_in[2];
    const int*   dst         = (const int*)d_in[3];
    const float* W1          = (const float*)d_in[4];
    const float* b1          = (const float*)d_in[5];
    const float* mu1         = (const float*)d_in[6];
    const float* is1         = (const float*)d_in[7];
    const float* W2          = (const float*)d_in[8];
    const float* b2          = (const float*)d_in[9];
    const float* mu2         = (const float*)d_in[10];
    const float* is2         = (const float*)d_in[11];
    float* out = (float*)d_out;

    // Workspace: csr int2[800k] | tmp int2[800k] | h1 half[3.2M] | h2 half[2M]
    //            | counts[50k] | partials[256] | cursor[50k] | offsets[50k+1]
    int2*   csr     = (int2*)d_ws;
    int2*   tmp     = csr + N_EDGES;
    __half* h1      = (__half*)(tmp + N_EDGES);
    __half* h2      = h1 + (size_t)N_NODES * N_HIDDEN;
    int*    counts  = (int*)(h2 + (size_t)N_NODES * OUT_FEATS);
    int*    partials= counts + N_NODES;          // 256 slots (196 used)
    int*    cursor  = partials + 256;
    int*    offsets = cursor + N_NODES;

    // one memset covers counts + partials (contiguous)
    hipMemsetAsync(counts, 0, (N_NODES + 256) * sizeof(int), stream);

    combo_kernel<<<EDGE_BLOCKS + GT_TILES, 256, 0, stream>>>(
        features, W1, src, dst, edge_weight, mu1, is1, mu2, is2, counts, tmp, h1);

    scan_kernel<<<SCAN_NB, 256, 0, stream>>>(counts, offsets, cursor, partials);

    fill_kernel<<<(N_EDGES + 255) / 256, 256, 0, stream>>>(dst, tmp, cursor, csr);

    agg1_gemm2_kernel<<<N_NODES / 4, 256, 0, stream>>>(h1, offsets, csr, b1, W2, h2);

    agg2_kernel<<<(N_NODES + 3) / 4, 256, 0, stream>>>(h2, offsets, csr, b2, out);
}